// Round 18
// baseline (402.415 us; speedup 1.0000x reference)
//
#include <hip/hip_runtime.h>
#include <hip/hip_bf16.h>
#include <stdint.h>

// Problem constants (fixed for this benchmark)
#define HIDDEN 3584
#define NH 28
#define NKV 4
#define HD 128
#define GQ (NH / NKV)                 // 7
#define NQKV ((NH + 2 * NKV) * HD)    // 4608
#define LSAMP 1024                    // S_TOT / N_SAMPLES

typedef __bf16 bf16x8 __attribute__((ext_vector_type(8)));
typedef float f32x4 __attribute__((ext_vector_type(4)));

__device__ __forceinline__ unsigned short f2bf(float f) {
  unsigned int u = __float_as_uint(f);
  u += 0x7fffu + ((u >> 16) & 1u);   // RNE
  return (unsigned short)(u >> 16);
}
__device__ __forceinline__ float bf2f(unsigned short h) {
  return __uint_as_float(((unsigned int)h) << 16);
}

__device__ __forceinline__ void gload16(const void* g, void* l) {
  __builtin_amdgcn_global_load_lds(
      (const __attribute__((address_space(1))) void*)g,
      (__attribute__((address_space(3))) void*)l, 16, 0, 0);
}

// ---------------------------------------------------------------- maps
__global__ void build_maps_kernel(const int* __restrict__ und, const int* __restrict__ geo,
                                  int nu, int ng,
                                  int* __restrict__ row_of_token, int* __restrict__ tok_of_row,
                                  int* __restrict__ mod_of_token) {
  int i = blockIdx.x * 256 + threadIdx.x;
  if (i < nu) {
    int t = und[i];
    row_of_token[t] = i; tok_of_row[i] = t; mod_of_token[t] = 0;
  } else if (i < nu + ng) {
    int j = i - nu;
    int t = geo[j];
    row_of_token[t] = nu + j; tok_of_row[nu + j] = t; mod_of_token[t] = 1;
  }
}

// ---------------------------------------------------------------- fused f32->bf16 convert (8 weight segments) + X gather tail
struct Cvt8 {
  const float* src[8];
  unsigned short* dst[8];
  int cum[8];
};
__global__ void convert_gather_kernel(Cvt8 a, int cvt4,
                                      const float* __restrict__ X,
                                      const int* __restrict__ tok_of_row,
                                      unsigned short* __restrict__ Xg, int tot4) {
  int i = blockIdx.x * blockDim.x + threadIdx.x;
  const int stride = gridDim.x * blockDim.x;
  for (; i < tot4; i += stride) {
    if (i < cvt4) {
      int seg = 0;
#pragma unroll
      for (int s2 = 1; s2 < 8; ++s2) seg += (i >= a.cum[s2]);
      const int off = i - a.cum[seg];
      float4 v = reinterpret_cast<const float4*>(a.src[seg])[off];
      reinterpret_cast<ushort4*>(a.dst[seg])[off] =
          make_ushort4(f2bf(v.x), f2bf(v.y), f2bf(v.z), f2bf(v.w));
    } else {
      const int gi = i - cvt4;
      const int r = gi / (HIDDEN / 4);
      const int c = gi - r * (HIDDEN / 4);
      const int tok = tok_of_row[r];
      float4 v = reinterpret_cast<const float4*>(X + (size_t)tok * HIDDEN)[c];
      reinterpret_cast<ushort4*>(Xg)[(size_t)r * (HIDDEN / 4) + c] =
          make_ushort4(f2bf(v.x), f2bf(v.y), f2bf(v.z), f2bf(v.w));
    }
  }
}

// ---------------------------------------------------------------- GEMM (R13/R14 verified 1-phase schedule, QKV control)
template <int OUTMODE, int NT, int WR, int WC, int NF>
__global__ __launch_bounds__(NT, (NT / 64 + 3) / 4)
void gemm2_kernel(const unsigned short* __restrict__ A,
                  const unsigned short* __restrict__ W0, const unsigned short* __restrict__ W1,
                  const float* __restrict__ qb0, const float* __restrict__ kb0, const float* __restrict__ vb0,
                  const float* __restrict__ qb1, const float* __restrict__ kb1, const float* __restrict__ vb1,
                  unsigned short* __restrict__ Obf, float* __restrict__ Of32,
                  const int* __restrict__ tok_of_row,
                  int nu, int ng, int N, int K, int NX, int NY) {
  constexpr int MF = 256 / WR / 16;
  constexpr int BN = WC * NF * 16;
  constexpr int BUFSZ = 32768 + BN * 128;
  constexpr int ACH = 2048;
  constexpr int BCH = BN * 8;
  __shared__ char lds[2 * BUFSZ];

  const int nwg = NX * NY * 2;
  int id = blockIdx.x + NX * (blockIdx.y + NY * blockIdx.z);
  {
    const int q = nwg >> 3, r = nwg & 7;
    const int xcd = id & 7, pos = id >> 3;
    id = (xcd < r ? xcd * (q + 1) : r * (q + 1) + (xcd - r) * q) + pos;
  }
  const int bx = id % NX;
  const int byz = id / NX;
  const int by = byz % NY;
  const int bz = byz / NY;

  const int baseRow = bz ? nu : 0;
  const int Mcount = bz ? ng : nu;
  const int mbase = by * 256;
  if (mbase >= Mcount) return;
  const unsigned short* W = bz ? W1 : W0;

  const int t = threadIdx.x;
  const int w = t >> 6, l = t & 63;
  const int l15 = l & 15, l4 = l >> 4;
  const int wr = w / WC, wc = w % WC;
  const int wrr = wr * (MF * 16), wcc = wc * (NF * 16);
  const int ncol0 = bx * BN;
  const int krev = w & 1;

  f32x4 acc[MF][NF] = {};

  const int nk = K >> 6;

  auto stage = [&](int bufIdx, int kt) {
    char* base = lds + bufIdx * BUFSZ;
    const int k0 = kt * 64;
#pragma unroll
    for (int c0 = 0; c0 < ACH; c0 += NT) {
      const int c = c0 + t;
      if (c < ACH) {
        const int row = c >> 3, slot = c & 7;
        const int srck = (slot ^ (row & 7)) << 3;
        int ar = mbase + row; if (ar >= Mcount) ar = Mcount - 1;
        gload16(A + (size_t)(baseRow + ar) * K + k0 + srck, base + c * 16);
      }
    }
#pragma unroll
    for (int c0 = 0; c0 < BCH; c0 += NT) {
      const int c = c0 + t;
      if (c < BCH) {
        const int row = c >> 3, slot = c & 7;
        const int srck = (slot ^ (row & 7)) << 3;
        gload16(W + (size_t)(ncol0 + row) * K + k0 + srck, base + 32768 + c * 16);
      }
    }
  };

  stage(0, 0);
  asm volatile("s_waitcnt vmcnt(0)\n\ts_barrier" ::: "memory");

  for (int kt = 0; kt < nk; ++kt) {
    char* Ab = lds + (kt & 1) * BUFSZ;
    char* Bb = Ab + 32768;

    if (kt + 1 < nk) stage((kt + 1) & 1, kt + 1);
    __builtin_amdgcn_sched_barrier(0);

#pragma unroll
    for (int ks = 0; ks < 2; ++ks) {
      const int kss = krev ? (1 - ks) : ks;
      bf16x8 af[MF], bfr[NF];
#pragma unroll
      for (int mf = 0; mf < MF; ++mf) {
        const int row = wrr + mf * 16 + l15;
        af[mf] = *reinterpret_cast<const bf16x8*>(Ab + row * 128 + (((kss * 4 + l4) ^ (row & 7)) << 4));
      }
#pragma unroll
      for (int nf = 0; nf < NF; ++nf) {
        const int row = wcc + nf * 16 + l15;
        bfr[nf] = *reinterpret_cast<const bf16x8*>(Bb + row * 128 + (((kss * 4 + l4) ^ (row & 7)) << 4));
      }
      __builtin_amdgcn_s_setprio(1);
#pragma unroll
      for (int mf = 0; mf < MF; ++mf)
#pragma unroll
        for (int nf = 0; nf < NF; ++nf)
          acc[mf][nf] = __builtin_amdgcn_mfma_f32_16x16x32_bf16(af[mf], bfr[nf], acc[mf][nf], 0, 0, 0);
      __builtin_amdgcn_s_setprio(0);
    }

    if (kt + 1 < nk) {
      asm volatile("s_waitcnt vmcnt(0)\n\ts_barrier" ::: "memory");
    }
  }

#pragma unroll
  for (int mf = 0; mf < MF; ++mf) {
#pragma unroll
    for (int rr = 0; rr < 4; ++rr) {
      const int ml = mbase + wrr + mf * 16 + l4 * 4 + rr;
      if (ml >= Mcount) continue;
      int trow = 0;
      if (OUTMODE == 1) trow = tok_of_row[baseRow + ml];
#pragma unroll
      for (int nf = 0; nf < NF; ++nf) {
        const int n = ncol0 + wcc + nf * 16 + l15;
        const float v = acc[mf][nf][rr];
        if (OUTMODE == 0) {
          const float* qb = bz ? qb1 : qb0;
          const float* kb = bz ? kb1 : kb0;
          const float* vb = bz ? vb1 : vb0;
          const float bias = (n < NH * HD) ? qb[n]
                              : ((n < (NH + NKV) * HD) ? kb[n - NH * HD] : vb[n - (NH + NKV) * HD]);
          Obf[(size_t)(baseRow + ml) * N + n] = f2bf(v + bias);
        } else {
          Of32[(size_t)trow * N + n] = v;
        }
      }
    }
  }
}

// ---------------------------------------------------------------- GEMM 256x256 4-phase m201-geometry (TREATMENT, O-proj)
// 8 waves (2M x 4N), wave tile 128x64, BK=64, LDS 2x(A 32KB + B 32KB)=128KB.
// Per K-tile, 4 quadrant phases (mh,ks): {reads 4xA [+4xB on new ks];
// distributed stage (A-chunks ph0, B-chunks ph1 -> 2-3 phases of slack);
// barrier; sched_barrier; setprio(1); 16 MFMA; setprio(0); barrier}.
// Boundary: vmcnt(0)+barrier. No intra-tile LDS write hazards (DMA targets
// the other buffer) -> phase barriers are pure scheduling rhythm.
__global__ __launch_bounds__(512, 2)
void gemm256o_kernel(const unsigned short* __restrict__ A,
                     const unsigned short* __restrict__ W0, const unsigned short* __restrict__ W1,
                     float* __restrict__ Of32, const int* __restrict__ tok_of_row,
                     int nu, int ng, int N, int K, int NX, int NY) {
  __shared__ char lds[131072];
  const int nwg = NX * NY * 2;        // 224 -> divisible by 8
  int id = blockIdx.x + NX * (blockIdx.y + NY * blockIdx.z);
  {
    const int q = nwg >> 3, r = nwg & 7;
    const int xcd = id & 7, pos = id >> 3;
    id = (xcd < r ? xcd * (q + 1) : r * (q + 1) + (xcd - r) * q) + pos;
  }
  const int bx = id % NX;
  const int byz = id / NX;
  const int by = byz % NY;
  const int bz = byz / NY;

  const int baseRow = bz ? nu : 0;
  const int Mcount = bz ? ng : nu;
  const int mbase = by * 256;
  if (mbase >= Mcount) return;
  const unsigned short* W = bz ? W1 : W0;

  const int t = threadIdx.x;
  const int w = t >> 6, l = t & 63;
  const int l15 = l & 15, l4 = l >> 4;
  const int wr = w >> 2, wc = w & 3;          // 2M x 4N
  const int wrr = wr * 128, wcc = wc * 64;
  const int ncol0 = bx * 256;

  f32x4 acc[8][4] = {};
  const int nk = K >> 6;

  auto stageA = [&](int bufIdx, int kt) {
    char* base = lds + bufIdx * 65536;
    const int k0 = kt * 64;
#pragma unroll
    for (int i = 0; i < 4; ++i) {             // A: 256 x 64 = 2048 chunks
      const int c = t + i * 512;
      const int row = c >> 3, slot = c & 7;
      const int srck = (slot ^ (row & 7)) << 3;
      int ar = mbase + row; if (ar >= Mcount) ar = Mcount - 1;
      gload16(A + (size_t)(baseRow + ar) * K + k0 + srck, base + c * 16);
    }
  };
  auto stageB = [&](int bufIdx, int kt) {
    char* base = lds + bufIdx * 65536 + 32768;
    const int k0 = kt * 64;
#pragma unroll
    for (int i = 0; i < 4; ++i) {             // B: 256 x 64 = 2048 chunks
      const int c = t + i * 512;
      const int row = c >> 3, slot = c & 7;
      const int srck = (slot ^ (row & 7)) << 3;
      gload16(W + (size_t)(ncol0 + row) * K + k0 + srck, base + c * 16);
    }
  };

  stageA(0, 0); stageB(0, 0);
  asm volatile("s_waitcnt vmcnt(0)\n\ts_barrier" ::: "memory");

  for (int kt = 0; kt < nk; ++kt) {
    char* Ab = lds + (kt & 1) * 65536;
    char* Bb = Ab + 32768;
    const bool pre = (kt + 1 < nk);
    const int nb = (kt + 1) & 1;
    bf16x8 af[4], bfr[4];

    // ---- phase 0: (mh0, ks0) reads + stage A(next)
#pragma unroll
    for (int mf = 0; mf < 4; ++mf) {
      const int row = wrr + mf * 16 + l15;
      af[mf] = *reinterpret_cast<const bf16x8*>(Ab + row * 128 + ((l4 ^ (row & 7)) << 4));
    }
#pragma unroll
    for (int nf = 0; nf < 4; ++nf) {
      const int row = wcc + nf * 16 + l15;
      bfr[nf] = *reinterpret_cast<const bf16x8*>(Bb + row * 128 + ((l4 ^ (row & 7)) << 4));
    }
    if (pre) stageA(nb, kt + 1);
    asm volatile("s_barrier" ::: "memory");
    __builtin_amdgcn_sched_barrier(0);
    __builtin_amdgcn_s_setprio(1);
#pragma unroll
    for (int mf = 0; mf < 4; ++mf)
#pragma unroll
      for (int nf = 0; nf < 4; ++nf)
        acc[mf][nf] = __builtin_amdgcn_mfma_f32_16x16x32_bf16(af[mf], bfr[nf], acc[mf][nf], 0, 0, 0);
    __builtin_amdgcn_s_setprio(0);
    asm volatile("s_barrier" ::: "memory");

    // ---- phase 1: (mh1, ks0) reads A only + stage B(next)
#pragma unroll
    for (int mf = 0; mf < 4; ++mf) {
      const int row = wrr + 64 + mf * 16 + l15;
      af[mf] = *reinterpret_cast<const bf16x8*>(Ab + row * 128 + ((l4 ^ (row & 7)) << 4));
    }
    if (pre) stageB(nb, kt + 1);
    asm volatile("s_barrier" ::: "memory");
    __builtin_amdgcn_sched_barrier(0);
    __builtin_amdgcn_s_setprio(1);
#pragma unroll
    for (int mf = 0; mf < 4; ++mf)
#pragma unroll
      for (int nf = 0; nf < 4; ++nf)
        acc[4 + mf][nf] = __builtin_amdgcn_mfma_f32_16x16x32_bf16(af[mf], bfr[nf], acc[4 + mf][nf], 0, 0, 0);
    __builtin_amdgcn_s_setprio(0);
    asm volatile("s_barrier" ::: "memory");

    // ---- phase 2: (mh0, ks1) reads A + B
#pragma unroll
    for (int mf = 0; mf < 4; ++mf) {
      const int row = wrr + mf * 16 + l15;
      af[mf] = *reinterpret_cast<const bf16x8*>(Ab + row * 128 + (((4 + l4) ^ (row & 7)) << 4));
    }
#pragma unroll
    for (int nf = 0; nf < 4; ++nf) {
      const int row = wcc + nf * 16 + l15;
      bfr[nf] = *reinterpret_cast<const bf16x8*>(Bb + row * 128 + (((4 + l4) ^ (row & 7)) << 4));
    }
    asm volatile("s_barrier" ::: "memory");
    __builtin_amdgcn_sched_barrier(0);
    __builtin_amdgcn_s_setprio(1);
#pragma unroll
    for (int mf = 0; mf < 4; ++mf)
#pragma unroll
      for (int nf = 0; nf < 4; ++nf)
        acc[mf][nf] = __builtin_amdgcn_mfma_f32_16x16x32_bf16(af[mf], bfr[nf], acc[mf][nf], 0, 0, 0);
    __builtin_amdgcn_s_setprio(0);
    asm volatile("s_barrier" ::: "memory");

    // ---- phase 3: (mh1, ks1) reads A only; boundary wait folds into closing barrier
#pragma unroll
    for (int mf = 0; mf < 4; ++mf) {
      const int row = wrr + 64 + mf * 16 + l15;
      af[mf] = *reinterpret_cast<const bf16x8*>(Ab + row * 128 + (((4 + l4) ^ (row & 7)) << 4));
    }
    asm volatile("s_barrier" ::: "memory");
    __builtin_amdgcn_sched_barrier(0);
    __builtin_amdgcn_s_setprio(1);
#pragma unroll
    for (int mf = 0; mf < 4; ++mf)
#pragma unroll
      for (int nf = 0; nf < 4; ++nf)
        acc[4 + mf][nf] = __builtin_amdgcn_mfma_f32_16x16x32_bf16(af[mf], bfr[nf], acc[4 + mf][nf], 0, 0, 0);
    __builtin_amdgcn_s_setprio(0);

    if (pre) {
      // next tile's 8 loads were issued in ph0/ph1 (~2-3 phases ago) -> mostly landed
      asm volatile("s_waitcnt vmcnt(0)\n\ts_barrier" ::: "memory");
    }
  }

  // ---- epilogue: f32 scatter to token rows
#pragma unroll
  for (int mf = 0; mf < 8; ++mf) {
#pragma unroll
    for (int rr = 0; rr < 4; ++rr) {
      const int ml = mbase + wrr + mf * 16 + l4 * 4 + rr;
      if (ml >= Mcount) continue;
      const int trow = tok_of_row[baseRow + ml];
#pragma unroll
      for (int nf = 0; nf < 4; ++nf) {
        const int n = ncol0 + wcc + nf * 16 + l15;
        Of32[(size_t)trow * N + n] = acc[mf][nf][rr];
      }
    }
  }
}

// ---------------------------------------------------------------- RMSNorm + MROPE + V transpose (vectorized, verified R14)
__global__ __launch_bounds__(64)
void norm_rope_kernel(const unsigned short* __restrict__ Y,
                      const int* __restrict__ row_of_token, const int* __restrict__ mod_of_token,
                      const float* __restrict__ pcos, const float* __restrict__ psin,
                      const float* __restrict__ qn_u, const float* __restrict__ kn_u,
                      const float* __restrict__ qn_g, const float* __restrict__ kn_g,
                      unsigned short* __restrict__ Qr,
                      unsigned short* __restrict__ Kr,
                      unsigned short* __restrict__ Vt,
                      int S) {
  const int s = blockIdx.x, l = threadIdx.x;
  const int g = l >> 4, l15 = l & 15;
  const int d0 = l15 * 8;
  const int axis = (d0 < 32) ? 0 : (d0 < 80 ? 1 : 2);
  const int r = row_of_token[s];
  const int m = mod_of_token[s];
  const float* qn = m ? qn_g : qn_u;
  const float* kn = m ? kn_g : kn_u;
  const bool hi = l15 >= 8;
  const float rsign = hi ? 1.f : -1.f;
  constexpr float SC = 0.08838834764831845f;

  float c8[8], s8[8], qw8[8], kw8[8];
  {
    const float* cp = pcos + ((size_t)axis * S + s) * HD + d0;
    const float* sp = psin + ((size_t)axis * S + s) * HD + d0;
#pragma unroll
    for (int j = 0; j < 8; ++j) { c8[j] = cp[j]; s8[j] = sp[j]; }
#pragma unroll
    for (int j = 0; j < 8; ++j) { qw8[j] = qn[d0 + j]; kw8[j] = kn[d0 + j]; }
  }
  const unsigned short* yrow = Y + (size_t)r * NQKV;

#pragma unroll
  for (int grp = 0; grp < 7; ++grp) {
    const int hh = grp * 4 + g;
    const bf16x8 y = *reinterpret_cast<const bf16x8*>(yrow + hh * HD + d0);
    float x[8], xw[8];
    float ss = 0.f;
#pragma unroll
    for (int j = 0; j < 8; ++j) { x[j] = bf2f(((unsigned short*)&y)[j]); ss += x[j] * x[j]; }
#pragma unroll
    for (int dd = 1; dd < 16; dd <<= 1) ss += __shfl_xor(ss, dd);
    const float rs = rsqrtf(ss * (1.f / 128.f) + 1e-6f) * SC;
#pragma unroll
    for (int j = 0; j < 8; ++j) xw[j] = x[j] * qw8[j];
    unsigned short o[8];
#pragma unroll
    for (int j = 0; j < 8; ++j) {
      const float xp = __shfl_xor(xw[j], 8);
      o[j] = f2bf(rs * (xw[j] * c8[j] + rsign * xp * s8[j]));
    }
    *reinterpret_cast<ushort4*>(Qr + ((size_t)hh * S + s) * HD + d0) = make_ushort4(o[0], o[1], o[2], o[3]);
    *reinterpret_cast<ushort4*>(Qr + ((size_t)hh * S + s) * HD + d0 + 4) = make_ushort4(o[4], o[5], o[6], o[7]);
  }

  {
    const int kh = g;
    const bf16x8 y = *reinterpret_cast<const bf16x8*>(yrow + (NH + kh) * HD + d0);
    float x[8], xw[8];
    float ss = 0.f;
#pragma unroll
    for (int j = 0; j < 8; ++j) { x[j] = bf2f(((unsigned short*)&y)[j]); ss += x[j] * x[j]; }
#pragma unroll
    for (int dd = 1; dd < 16; dd <<= 1) ss += __shfl_xor(ss, dd);
    const float rs = rsqrtf(ss * (1.f / 128.f) + 1e-6f);
#pragma unroll
    for (int j = 0; j < 8; ++j) xw[j] = x[j] * kw8[j];
    unsigned short o[8];
#pragma unroll
    for (int j = 0; j < 8; ++j) {
      const float xp = __shfl_xor(xw[j], 8);
      o[j] = f2bf(rs * (xw[j] * c8[j] + rsign * xp * s8[j]));
    }
    *reinterpret_cast<ushort4*>(Kr + ((size_t)kh * S + s) * HD + d0) = make_ushort4(o[0], o[1], o[2], o[3]);
    *reinterpret_cast<ushort4*>(Kr + ((size_t)kh * S + s) * HD + d0 + 4) = make_ushort4(o[4], o[5], o[6], o[7]);
  }

  {
    const int vh = g;
    const bf16x8 y = *reinterpret_cast<const bf16x8*>(yrow + (NH + NKV + vh) * HD + d0);
#pragma unroll
    for (int j = 0; j < 8; ++j)
      Vt[((size_t)(vh * HD + d0 + j)) * S + s] = ((unsigned short*)&y)[j];
  }
}

// ---------------------------------------------------------------- flash attention v2 (verified R14)
__global__ __launch_bounds__(448, 1)
void attn7_kernel(const unsigned short* __restrict__ Qr, const unsigned short* __restrict__ Kr,
                  const unsigned short* __restrict__ Vt, const int* __restrict__ row_of_token,
                  unsigned short* __restrict__ Og, int S) {
  __shared__ char lds[2 * 16384 + 2 * 16384 + 7 * 4608];
  const int kvh = blockIdx.y, b = blockIdx.z;
  const int t = threadIdx.x, w = t >> 6, l = t & 63;
  const int l15 = l & 15, l4 = l >> 4;
  const int h = kvh * GQ + w;
  const int sbase = b * LSAMP;
  char* Plds = lds + 65536 + w * 4608;

  auto stage = [&](int bufIdx, int kt) {
    char* Kb = lds + bufIdx * 16384;
    char* Vb = lds + 32768 + bufIdx * 16384;
    const int kb0 = sbase + kt * 64;
    for (int c = t; c < 1024; c += 448) {
      const int row = c >> 4, slot = c & 15;
      const int srcs = slot ^ (row & 15);
      gload16(Kr + ((size_t)kvh * S + kb0 + row) * HD + srcs * 8, Kb + c * 16);
    }
    for (int c = t; c < 1024; c += 448) {
      const int row = c >> 3, slot = c & 7;
      const int srcs = slot ^ (row & 7);
      gload16(Vt + (size_t)(kvh * HD + row) * S + kb0 + srcs * 8, Vb + c * 16);
    }
  };

  for (int pass = 0; pass < 2; ++pass) {
    const int q32 = pass ? (31 - blockIdx.x) : blockIdx.x;
    const int nkt = q32 / 2 + 1;

    bf16x8 aq[2][4];
#pragma unroll
    for (int fr = 0; fr < 2; ++fr) {
      const int qrow = sbase + q32 * 32 + fr * 16 + l15;
      const unsigned short* qp = Qr + ((size_t)h * S + qrow) * HD + l4 * 8;
#pragma unroll
      for (int kk = 0; kk < 4; ++kk) aq[fr][kk] = *reinterpret_cast<const bf16x8*>(qp + kk * 32);
    }
    f32x4 acc[2][8] = {};
    float mr[2][4], lr[2][4];
#pragma unroll
    for (int fr = 0; fr < 2; ++fr)
#pragma unroll
      for (int rr = 0; rr < 4; ++rr) { mr[fr][rr] = -INFINITY; lr[fr][rr] = 0.f; }

    stage(0, 0);
    asm volatile("s_waitcnt vmcnt(0)\n\ts_barrier" ::: "memory");

    for (int kt = 0; kt < nkt; ++kt) {
      char* Kb = lds + (kt & 1) * 16384;
      char* Vb = lds + 32768 + (kt & 1) * 16384;

      if (kt + 1 < nkt) stage((kt + 1) & 1, kt + 1);
      __builtin_amdgcn_sched_barrier(0);

      f32x4 sa[2][4] = {};
#pragma unroll
      for (int kk = 0; kk < 4; ++kk) {
        bf16x8 bk[4];
#pragma unroll
        for (int nf = 0; nf < 4; ++nf) {
          const int row = nf * 16 + l15;
          const int slot = kk * 4 + l4;
          bk[nf] = *reinterpret_cast<const bf16x8*>(Kb + row * 256 + ((slot ^ (row & 15)) << 4));
        }
#pragma unroll
        for (int fr = 0; fr < 2; ++fr)
#pragma unroll
          for (int nf = 0; nf < 4; ++nf)
            sa[fr][nf] = __builtin_amdgcn_mfma_f32_16x16x32_bf16(aq[fr][kk], bk[nf], sa[fr][nf], 0, 0, 0);
      }

#pragma unroll
      for (int fr = 0; fr < 2; ++fr) {
        const int qg = q32 * 32 + fr * 16 + l4 * 4;
#pragma unroll
        for (int nf = 0; nf < 4; ++nf) {
          const int cg = kt * 64 + nf * 16 + l15;
#pragma unroll
          for (int rr = 0; rr < 4; ++rr)
            if (cg > qg + rr) sa[fr][nf][rr] = -INFINITY;
        }
#pragma unroll
        for (int rr = 0; rr < 4; ++rr) {
          float mx = fmaxf(fmaxf(sa[fr][0][rr], sa[fr][1][rr]), fmaxf(sa[fr][2][rr], sa[fr][3][rr]));
          mx = fmaxf(mx, mr[fr][rr]);
#pragma unroll
          for (int dd = 1; dd < 16; dd <<= 1) mx = fmaxf(mx, __shfl_xor(mx, dd));
          const float alpha = __expf(mr[fr][rr] - mx);
          mr[fr][rr] = mx;
          float part = 0.f;
#pragma unroll
          for (int nf = 0; nf < 4; ++nf) {
            const float p = __expf(sa[fr][nf][rr] - mx);
            sa[fr][nf][rr] = p;
            part += p;
          }
          lr[fr][rr] = lr[fr][rr] * alpha + part;
#pragma unroll
          for (int nf2 = 0; nf2 < 8; ++nf2) acc[fr][nf2][rr] *= alpha;
        }
#pragma unroll
        for (int rr = 0; rr < 4; ++rr) {
          const int row = fr * 16 + l4 * 4 + rr;
#pragma unroll
          for (int nf = 0; nf < 4; ++nf)
            ((unsigned short*)(Plds + row * 144))[nf * 16 + l15] = f2bf(sa[fr][nf][rr]);
        }
      }

#pragma unroll
      for (int kk2 = 0; kk2 < 2; ++kk2) {
        bf16x8 ap[2];
#pragma unroll
        for (int fr = 0; fr < 2; ++fr)
          ap[fr] = *reinterpret_cast<const bf16x8*>(Plds + (fr * 16 + l15) * 144 + kk2 * 64 + l4 * 16);
#pragma unroll
        for (int nf2 = 0; nf2 < 8; ++nf2) {
          const int rowd = nf2 * 16 + l15;
          const int slot = kk2 * 4 + l4;
          const bf16x8 bv = *reinterpret_cast<const bf16x8*>(Vb + rowd * 128 + ((slot ^ (rowd & 7)) << 4));
#pragma unroll
          for (int fr = 0; fr < 2; ++fr)
            acc[fr][nf2] = __builtin_amdgcn_mfma_f32_16x16x32_bf16(ap[fr], bv, acc[fr][nf2], 0, 0, 0);
        }
      }

      if (kt + 1 < nkt) {
        asm volatile("s_waitcnt vmcnt(0)\n\ts_barrier" ::: "memory");
      }
    }

#pragma unroll
    for (int fr = 0; fr < 2; ++fr) {
#pragma unroll
      for (int rr = 0; rr < 4; ++rr) {
#pragma unroll
        for (int dd = 1; dd < 16; dd <<= 1) lr[fr][rr] += __shfl_xor(lr[fr][rr], dd);
        const float inv = 1.f / lr[fr][rr];
        const int srow = sbase + q32 * 32 + fr * 16 + l4 * 4 + rr;
        const int mrow = row_of_token[srow];
        unsigned short* orow = Og + (size_t)mrow * (NH * HD) + h * HD;
#pragma unroll
        for (int nf2 = 0; nf2 < 8; ++nf2) orow[nf2 * 16 + l15] = f2bf(acc[fr][nf2][rr] * inv);
      }
    }

    if (pass == 0) {
      asm volatile("s_waitcnt vmcnt(0) lgkmcnt(0)\n\ts_barrier" ::: "memory");
    }
  }
}

// ---------------------------------------------------------------- launch
extern "C" void kernel_launch(void* const* d_in, const int* in_sizes, int n_in,
                              void* d_out, int out_size, void* d_ws, size_t ws_size,
                              hipStream_t stream) {
  const float* X = (const float*)d_in[0];
  const float* pcos = (const float*)d_in[1];
  const float* psin = (const float*)d_in[2];
  const int* und = (const int*)d_in[3];
  const int* geo = (const int*)d_in[4];
  const int nu = in_sizes[3], ng = in_sizes[4];
  const int S = in_sizes[0] / HIDDEN;

  const float* qw[2] = {(const float*)d_in[6], (const float*)d_in[15]};
  const float* qb[2] = {(const float*)d_in[7], (const float*)d_in[16]};
  const float* kw[2] = {(const float*)d_in[8], (const float*)d_in[17]};
  const float* kb[2] = {(const float*)d_in[9], (const float*)d_in[18]};
  const float* vw[2] = {(const float*)d_in[10], (const float*)d_in[19]};
  const float* vb[2] = {(const float*)d_in[11], (const float*)d_in[20]};
  const float* ow[2] = {(const float*)d_in[12], (const float*)d_in[21]};
  const float* qn[2] = {(const float*)d_in[13], (const float*)d_in[22]};
  const float* kn[2] = {(const float*)d_in[14], (const float*)d_in[23]};

  char* ws = (char*)d_ws;
  size_t off = 0;
  auto alloc = [&](size_t bytes) {
    char* p = ws + off;
    off = (off + bytes + 255) & ~(size_t)255;
    return p;
  };
  int* row_of_token = (int*)alloc((size_t)S * 4);
  int* tok_of_row = (int*)alloc((size_t)S * 4);
  int* mod_of_token = (int*)alloc((size_t)S * 4);
  unsigned short* Wqkv[2] = {(unsigned short*)alloc((size_t)NQKV * HIDDEN * 2),
                             (unsigned short*)alloc((size_t)NQKV * HIDDEN * 2)};
  unsigned short* Wo[2] = {(unsigned short*)alloc((size_t)HIDDEN * HIDDEN * 2),
                           (unsigned short*)alloc((size_t)HIDDEN * HIDDEN * 2)};
  unsigned short* Xg = (unsigned short*)alloc((size_t)S * HIDDEN * 2);
  unsigned short* Yqkv = (unsigned short*)alloc((size_t)S * NQKV * 2);
  unsigned short* Qr = (unsigned short*)alloc((size_t)NH * S * HD * 2);
  unsigned short* Kr = (unsigned short*)alloc((size_t)NKV * S * HD * 2);
  unsigned short* Vt = (unsigned short*)alloc((size_t)NKV * S * HD * 2);
  unsigned short* Og = (unsigned short*)alloc((size_t)S * NH * HD * 2);
  (void)ws_size; (void)n_in; (void)out_size;

  build_maps_kernel<<<(S + 255) / 256, 256, 0, stream>>>(und, geo, nu, ng,
                                                         row_of_token, tok_of_row, mod_of_token);
  {
    Cvt8 ca;
    const float* srcs[8] = {qw[0], kw[0], vw[0], ow[0], qw[1], kw[1], vw[1], ow[1]};
    unsigned short* dsts[8] = {
        Wqkv[0], Wqkv[0] + (size_t)NH * HD * HIDDEN, Wqkv[0] + (size_t)(NH + NKV) * HD * HIDDEN, Wo[0],
        Wqkv[1], Wqkv[1] + (size_t)NH * HD * HIDDEN, Wqkv[1] + (size_t)(NH + NKV) * HD * HIDDEN, Wo[1]};
    const int n4s[8] = {NH * HD * HIDDEN / 4, NKV * HD * HIDDEN / 4, NKV * HD * HIDDEN / 4, HIDDEN * HIDDEN / 4,
                        NH * HD * HIDDEN / 4, NKV * HD * HIDDEN / 4, NKV * HD * HIDDEN / 4, HIDDEN * HIDDEN / 4};
    int cum = 0;
    for (int i = 0; i < 8; ++i) { ca.src[i] = srcs[i]; ca.dst[i] = dsts[i]; ca.cum[i] = cum; cum += n4s[i]; }
    const int gather4 = S * (HIDDEN / 4);
    convert_gather_kernel<<<2048, 256, 0, stream>>>(ca, cum, X, tok_of_row, Xg, cum + gather4);
  }

  const int maxM = (nu > ng ? nu : ng);
  {
    // QKV (control): 12 waves (4x3), BN=288 (NF=6) -> 16x8x2 = 256 blocks
    const int NX = NQKV / 288, NY = (maxM + 255) / 256;
    gemm2_kernel<0, 768, 4, 3, 6><<<dim3(NX, NY, 2), 768, 0, stream>>>(
        Xg, Wqkv[0], Wqkv[1], qb[0], kb[0], vb[0], qb[1], kb[1], vb[1],
        Yqkv, nullptr, nullptr, nu, ng, NQKV, HIDDEN, NX, NY);
  }

  norm_rope_kernel<<<S, 64, 0, stream>>>(Yqkv, row_of_token, mod_of_token, pcos, psin,
                                         qn[0], kn[0], qn[1], kn[1], Qr, Kr, Vt, S);

  attn7_kernel<<<dim3(16, NKV, S / LSAMP), 448, 0, stream>>>(Qr, Kr, Vt, row_of_token, Og, S);

  {
    // O-proj (treatment): 256x256 m201-geometry 4-phase, 8 waves -> 14x8x2 = 224 blocks
    const int NX = HIDDEN / 256, NY = (maxM + 255) / 256;
    gemm256o_kernel<<<dim3(NX, NY, 2), 512, 0, stream>>>(
        Og, Wo[0], Wo[1], (float*)d_out, tok_of_row, nu, ng, HIDDEN, HIDDEN, NX, NY);
  }
}

// Round 19
// 390.163 us; speedup vs baseline: 1.0314x; 1.0314x over previous
//
#include <hip/hip_runtime.h>
#include <hip/hip_bf16.h>
#include <stdint.h>

// Problem constants (fixed for this benchmark)
#define HIDDEN 3584
#define NH 28
#define NKV 4
#define HD 128
#define GQ (NH / NKV)                 // 7
#define NQKV ((NH + 2 * NKV) * HD)    // 4608
#define LSAMP 1024                    // S_TOT / N_SAMPLES

typedef __bf16 bf16x8 __attribute__((ext_vector_type(8)));
typedef float f32x4 __attribute__((ext_vector_type(4)));

__device__ __forceinline__ unsigned short f2bf(float f) {
  unsigned int u = __float_as_uint(f);
  u += 0x7fffu + ((u >> 16) & 1u);   // RNE
  return (unsigned short)(u >> 16);
}
__device__ __forceinline__ float bf2f(unsigned short h) {
  return __uint_as_float(((unsigned int)h) << 16);
}

__device__ __forceinline__ void gload16(const void* g, void* l) {
  __builtin_amdgcn_global_load_lds(
      (const __attribute__((address_space(1))) void*)g,
      (__attribute__((address_space(3))) void*)l, 16, 0, 0);
}

// ---------------------------------------------------------------- maps
__global__ void build_maps_kernel(const int* __restrict__ und, const int* __restrict__ geo,
                                  int nu, int ng,
                                  int* __restrict__ row_of_token, int* __restrict__ tok_of_row,
                                  int* __restrict__ mod_of_token) {
  int i = blockIdx.x * 256 + threadIdx.x;
  if (i < nu) {
    int t = und[i];
    row_of_token[t] = i; tok_of_row[i] = t; mod_of_token[t] = 0;
  } else if (i < nu + ng) {
    int j = i - nu;
    int t = geo[j];
    row_of_token[t] = nu + j; tok_of_row[nu + j] = t; mod_of_token[t] = 1;
  }
}

// ---------------------------------------------------------------- fused f32->bf16 convert (8 weight segments) + X gather tail
struct Cvt8 {
  const float* src[8];
  unsigned short* dst[8];
  int cum[8];
};
__global__ void convert_gather_kernel(Cvt8 a, int cvt4,
                                      const float* __restrict__ X,
                                      const int* __restrict__ tok_of_row,
                                      unsigned short* __restrict__ Xg, int tot4) {
  int i = blockIdx.x * blockDim.x + threadIdx.x;
  const int stride = gridDim.x * blockDim.x;
  for (; i < tot4; i += stride) {
    if (i < cvt4) {
      int seg = 0;
#pragma unroll
      for (int s2 = 1; s2 < 8; ++s2) seg += (i >= a.cum[s2]);
      const int off = i - a.cum[seg];
      float4 v = reinterpret_cast<const float4*>(a.src[seg])[off];
      reinterpret_cast<ushort4*>(a.dst[seg])[off] =
          make_ushort4(f2bf(v.x), f2bf(v.y), f2bf(v.z), f2bf(v.w));
    } else {
      const int gi = i - cvt4;
      const int r = gi / (HIDDEN / 4);
      const int c = gi - r * (HIDDEN / 4);
      const int tok = tok_of_row[r];
      float4 v = reinterpret_cast<const float4*>(X + (size_t)tok * HIDDEN)[c];
      reinterpret_cast<ushort4*>(Xg)[(size_t)r * (HIDDEN / 4) + c] =
          make_ushort4(f2bf(v.x), f2bf(v.y), f2bf(v.z), f2bf(v.w));
    }
  }
}

// ---------------------------------------------------------------- GEMM (R13/R14 verified 1-phase schedule + ks stagger)
template <int OUTMODE, int NT, int WR, int WC, int NF>
__global__ __launch_bounds__(NT, (NT / 64 + 3) / 4)
void gemm2_kernel(const unsigned short* __restrict__ A,
                  const unsigned short* __restrict__ W0, const unsigned short* __restrict__ W1,
                  const float* __restrict__ qb0, const float* __restrict__ kb0, const float* __restrict__ vb0,
                  const float* __restrict__ qb1, const float* __restrict__ kb1, const float* __restrict__ vb1,
                  unsigned short* __restrict__ Obf, float* __restrict__ Of32,
                  const int* __restrict__ tok_of_row,
                  int nu, int ng, int N, int K, int NX, int NY) {
  constexpr int MF = 256 / WR / 16;
  constexpr int BN = WC * NF * 16;
  constexpr int BUFSZ = 32768 + BN * 128;
  constexpr int ACH = 2048;
  constexpr int BCH = BN * 8;
  __shared__ char lds[2 * BUFSZ];

  const int nwg = NX * NY * 2;
  int id = blockIdx.x + NX * (blockIdx.y + NY * blockIdx.z);
  {
    const int q = nwg >> 3, r = nwg & 7;
    const int xcd = id & 7, pos = id >> 3;
    id = (xcd < r ? xcd * (q + 1) : r * (q + 1) + (xcd - r) * q) + pos;
  }
  const int bx = id % NX;
  const int byz = id / NX;
  const int by = byz % NY;
  const int bz = byz / NY;

  const int baseRow = bz ? nu : 0;
  const int Mcount = bz ? ng : nu;
  const int mbase = by * 256;
  if (mbase >= Mcount) return;
  const unsigned short* W = bz ? W1 : W0;

  const int t = threadIdx.x;
  const int w = t >> 6, l = t & 63;
  const int l15 = l & 15, l4 = l >> 4;
  const int wr = w / WC, wc = w % WC;
  const int wrr = wr * (MF * 16), wcc = wc * (NF * 16);
  const int ncol0 = bx * BN;
  const int krev = w & 1;

  f32x4 acc[MF][NF] = {};

  const int nk = K >> 6;

  auto stage = [&](int bufIdx, int kt) {
    char* base = lds + bufIdx * BUFSZ;
    const int k0 = kt * 64;
#pragma unroll
    for (int c0 = 0; c0 < ACH; c0 += NT) {
      const int c = c0 + t;
      if (c < ACH) {
        const int row = c >> 3, slot = c & 7;
        const int srck = (slot ^ (row & 7)) << 3;
        int ar = mbase + row; if (ar >= Mcount) ar = Mcount - 1;
        gload16(A + (size_t)(baseRow + ar) * K + k0 + srck, base + c * 16);
      }
    }
#pragma unroll
    for (int c0 = 0; c0 < BCH; c0 += NT) {
      const int c = c0 + t;
      if (c < BCH) {
        const int row = c >> 3, slot = c & 7;
        const int srck = (slot ^ (row & 7)) << 3;
        gload16(W + (size_t)(ncol0 + row) * K + k0 + srck, base + 32768 + c * 16);
      }
    }
  };

  stage(0, 0);
  asm volatile("s_waitcnt vmcnt(0)\n\ts_barrier" ::: "memory");

  for (int kt = 0; kt < nk; ++kt) {
    char* Ab = lds + (kt & 1) * BUFSZ;
    char* Bb = Ab + 32768;

    if (kt + 1 < nk) stage((kt + 1) & 1, kt + 1);
    __builtin_amdgcn_sched_barrier(0);

#pragma unroll
    for (int ks = 0; ks < 2; ++ks) {
      const int kss = krev ? (1 - ks) : ks;
      bf16x8 af[MF], bfr[NF];
#pragma unroll
      for (int mf = 0; mf < MF; ++mf) {
        const int row = wrr + mf * 16 + l15;
        af[mf] = *reinterpret_cast<const bf16x8*>(Ab + row * 128 + (((kss * 4 + l4) ^ (row & 7)) << 4));
      }
#pragma unroll
      for (int nf = 0; nf < NF; ++nf) {
        const int row = wcc + nf * 16 + l15;
        bfr[nf] = *reinterpret_cast<const bf16x8*>(Bb + row * 128 + (((kss * 4 + l4) ^ (row & 7)) << 4));
      }
      __builtin_amdgcn_s_setprio(1);
#pragma unroll
      for (int mf = 0; mf < MF; ++mf)
#pragma unroll
        for (int nf = 0; nf < NF; ++nf)
          acc[mf][nf] = __builtin_amdgcn_mfma_f32_16x16x32_bf16(af[mf], bfr[nf], acc[mf][nf], 0, 0, 0);
      __builtin_amdgcn_s_setprio(0);
    }

    if (kt + 1 < nk) {
      asm volatile("s_waitcnt vmcnt(0)\n\ts_barrier" ::: "memory");
    }
  }

#pragma unroll
  for (int mf = 0; mf < MF; ++mf) {
#pragma unroll
    for (int rr = 0; rr < 4; ++rr) {
      const int ml = mbase + wrr + mf * 16 + l4 * 4 + rr;
      if (ml >= Mcount) continue;
      int trow = 0;
      if (OUTMODE == 1) trow = tok_of_row[baseRow + ml];
#pragma unroll
      for (int nf = 0; nf < NF; ++nf) {
        const int n = ncol0 + wcc + nf * 16 + l15;
        const float v = acc[mf][nf][rr];
        if (OUTMODE == 0) {
          const float* qb = bz ? qb1 : qb0;
          const float* kb = bz ? kb1 : kb0;
          const float* vb = bz ? vb1 : vb0;
          const float bias = (n < NH * HD) ? qb[n]
                              : ((n < (NH + NKV) * HD) ? kb[n - NH * HD] : vb[n - (NH + NKV) * HD]);
          Obf[(size_t)(baseRow + ml) * N + n] = f2bf(v + bias);
        } else {
          Of32[(size_t)trow * N + n] = v;
        }
      }
    }
  }
}

// ---------------------------------------------------------------- RMSNorm + MROPE + V transpose (vectorized, verified R14)
__global__ __launch_bounds__(64)
void norm_rope_kernel(const unsigned short* __restrict__ Y,
                      const int* __restrict__ row_of_token, const int* __restrict__ mod_of_token,
                      const float* __restrict__ pcos, const float* __restrict__ psin,
                      const float* __restrict__ qn_u, const float* __restrict__ kn_u,
                      const float* __restrict__ qn_g, const float* __restrict__ kn_g,
                      unsigned short* __restrict__ Qr,
                      unsigned short* __restrict__ Kr,
                      unsigned short* __restrict__ Vt,
                      int S) {
  const int s = blockIdx.x, l = threadIdx.x;
  const int g = l >> 4, l15 = l & 15;
  const int d0 = l15 * 8;
  const int axis = (d0 < 32) ? 0 : (d0 < 80 ? 1 : 2);
  const int r = row_of_token[s];
  const int m = mod_of_token[s];
  const float* qn = m ? qn_g : qn_u;
  const float* kn = m ? kn_g : kn_u;
  const bool hi = l15 >= 8;
  const float rsign = hi ? 1.f : -1.f;
  constexpr float SC = 0.08838834764831845f;

  float c8[8], s8[8], qw8[8], kw8[8];
  {
    const float* cp = pcos + ((size_t)axis * S + s) * HD + d0;
    const float* sp = psin + ((size_t)axis * S + s) * HD + d0;
#pragma unroll
    for (int j = 0; j < 8; ++j) { c8[j] = cp[j]; s8[j] = sp[j]; }
#pragma unroll
    for (int j = 0; j < 8; ++j) { qw8[j] = qn[d0 + j]; kw8[j] = kn[d0 + j]; }
  }
  const unsigned short* yrow = Y + (size_t)r * NQKV;

#pragma unroll
  for (int grp = 0; grp < 7; ++grp) {
    const int hh = grp * 4 + g;
    const bf16x8 y = *reinterpret_cast<const bf16x8*>(yrow + hh * HD + d0);
    float x[8], xw[8];
    float ss = 0.f;
#pragma unroll
    for (int j = 0; j < 8; ++j) { x[j] = bf2f(((unsigned short*)&y)[j]); ss += x[j] * x[j]; }
#pragma unroll
    for (int dd = 1; dd < 16; dd <<= 1) ss += __shfl_xor(ss, dd);
    const float rs = rsqrtf(ss * (1.f / 128.f) + 1e-6f) * SC;
#pragma unroll
    for (int j = 0; j < 8; ++j) xw[j] = x[j] * qw8[j];
    unsigned short o[8];
#pragma unroll
    for (int j = 0; j < 8; ++j) {
      const float xp = __shfl_xor(xw[j], 8);
      o[j] = f2bf(rs * (xw[j] * c8[j] + rsign * xp * s8[j]));
    }
    *reinterpret_cast<ushort4*>(Qr + ((size_t)hh * S + s) * HD + d0) = make_ushort4(o[0], o[1], o[2], o[3]);
    *reinterpret_cast<ushort4*>(Qr + ((size_t)hh * S + s) * HD + d0 + 4) = make_ushort4(o[4], o[5], o[6], o[7]);
  }

  {
    const int kh = g;
    const bf16x8 y = *reinterpret_cast<const bf16x8*>(yrow + (NH + kh) * HD + d0);
    float x[8], xw[8];
    float ss = 0.f;
#pragma unroll
    for (int j = 0; j < 8; ++j) { x[j] = bf2f(((unsigned short*)&y)[j]); ss += x[j] * x[j]; }
#pragma unroll
    for (int dd = 1; dd < 16; dd <<= 1) ss += __shfl_xor(ss, dd);
    const float rs = rsqrtf(ss * (1.f / 128.f) + 1e-6f);
#pragma unroll
    for (int j = 0; j < 8; ++j) xw[j] = x[j] * kw8[j];
    unsigned short o[8];
#pragma unroll
    for (int j = 0; j < 8; ++j) {
      const float xp = __shfl_xor(xw[j], 8);
      o[j] = f2bf(rs * (xw[j] * c8[j] + rsign * xp * s8[j]));
    }
    *reinterpret_cast<ushort4*>(Kr + ((size_t)kh * S + s) * HD + d0) = make_ushort4(o[0], o[1], o[2], o[3]);
    *reinterpret_cast<ushort4*>(Kr + ((size_t)kh * S + s) * HD + d0 + 4) = make_ushort4(o[4], o[5], o[6], o[7]);
  }

  {
    const int vh = g;
    const bf16x8 y = *reinterpret_cast<const bf16x8*>(yrow + (NH + NKV + vh) * HD + d0);
#pragma unroll
    for (int j = 0; j < 8; ++j)
      Vt[((size_t)(vh * HD + d0 + j)) * S + s] = ((unsigned short*)&y)[j];
  }
}

// ---------------------------------------------------------------- flash attention v2 (verified R14)
__global__ __launch_bounds__(448, 1)
void attn7_kernel(const unsigned short* __restrict__ Qr, const unsigned short* __restrict__ Kr,
                  const unsigned short* __restrict__ Vt, const int* __restrict__ row_of_token,
                  unsigned short* __restrict__ Og, int S) {
  __shared__ char lds[2 * 16384 + 2 * 16384 + 7 * 4608];
  const int kvh = blockIdx.y, b = blockIdx.z;
  const int t = threadIdx.x, w = t >> 6, l = t & 63;
  const int l15 = l & 15, l4 = l >> 4;
  const int h = kvh * GQ + w;
  const int sbase = b * LSAMP;
  char* Plds = lds + 65536 + w * 4608;

  auto stage = [&](int bufIdx, int kt) {
    char* Kb = lds + bufIdx * 16384;
    char* Vb = lds + 32768 + bufIdx * 16384;
    const int kb0 = sbase + kt * 64;
    for (int c = t; c < 1024; c += 448) {
      const int row = c >> 4, slot = c & 15;
      const int srcs = slot ^ (row & 15);
      gload16(Kr + ((size_t)kvh * S + kb0 + row) * HD + srcs * 8, Kb + c * 16);
    }
    for (int c = t; c < 1024; c += 448) {
      const int row = c >> 3, slot = c & 7;
      const int srcs = slot ^ (row & 7);
      gload16(Vt + (size_t)(kvh * HD + row) * S + kb0 + srcs * 8, Vb + c * 16);
    }
  };

  for (int pass = 0; pass < 2; ++pass) {
    const int q32 = pass ? (31 - blockIdx.x) : blockIdx.x;
    const int nkt = q32 / 2 + 1;

    bf16x8 aq[2][4];
#pragma unroll
    for (int fr = 0; fr < 2; ++fr) {
      const int qrow = sbase + q32 * 32 + fr * 16 + l15;
      const unsigned short* qp = Qr + ((size_t)h * S + qrow) * HD + l4 * 8;
#pragma unroll
      for (int kk = 0; kk < 4; ++kk) aq[fr][kk] = *reinterpret_cast<const bf16x8*>(qp + kk * 32);
    }
    f32x4 acc[2][8] = {};
    float mr[2][4], lr[2][4];
#pragma unroll
    for (int fr = 0; fr < 2; ++fr)
#pragma unroll
      for (int rr = 0; rr < 4; ++rr) { mr[fr][rr] = -INFINITY; lr[fr][rr] = 0.f; }

    stage(0, 0);
    asm volatile("s_waitcnt vmcnt(0)\n\ts_barrier" ::: "memory");

    for (int kt = 0; kt < nkt; ++kt) {
      char* Kb = lds + (kt & 1) * 16384;
      char* Vb = lds + 32768 + (kt & 1) * 16384;

      if (kt + 1 < nkt) stage((kt + 1) & 1, kt + 1);
      __builtin_amdgcn_sched_barrier(0);

      f32x4 sa[2][4] = {};
#pragma unroll
      for (int kk = 0; kk < 4; ++kk) {
        bf16x8 bk[4];
#pragma unroll
        for (int nf = 0; nf < 4; ++nf) {
          const int row = nf * 16 + l15;
          const int slot = kk * 4 + l4;
          bk[nf] = *reinterpret_cast<const bf16x8*>(Kb + row * 256 + ((slot ^ (row & 15)) << 4));
        }
#pragma unroll
        for (int fr = 0; fr < 2; ++fr)
#pragma unroll
          for (int nf = 0; nf < 4; ++nf)
            sa[fr][nf] = __builtin_amdgcn_mfma_f32_16x16x32_bf16(aq[fr][kk], bk[nf], sa[fr][nf], 0, 0, 0);
      }

#pragma unroll
      for (int fr = 0; fr < 2; ++fr) {
        const int qg = q32 * 32 + fr * 16 + l4 * 4;
#pragma unroll
        for (int nf = 0; nf < 4; ++nf) {
          const int cg = kt * 64 + nf * 16 + l15;
#pragma unroll
          for (int rr = 0; rr < 4; ++rr)
            if (cg > qg + rr) sa[fr][nf][rr] = -INFINITY;
        }
#pragma unroll
        for (int rr = 0; rr < 4; ++rr) {
          float mx = fmaxf(fmaxf(sa[fr][0][rr], sa[fr][1][rr]), fmaxf(sa[fr][2][rr], sa[fr][3][rr]));
          mx = fmaxf(mx, mr[fr][rr]);
#pragma unroll
          for (int dd = 1; dd < 16; dd <<= 1) mx = fmaxf(mx, __shfl_xor(mx, dd));
          const float alpha = __expf(mr[fr][rr] - mx);
          mr[fr][rr] = mx;
          float part = 0.f;
#pragma unroll
          for (int nf = 0; nf < 4; ++nf) {
            const float p = __expf(sa[fr][nf][rr] - mx);
            sa[fr][nf][rr] = p;
            part += p;
          }
          lr[fr][rr] = lr[fr][rr] * alpha + part;
#pragma unroll
          for (int nf2 = 0; nf2 < 8; ++nf2) acc[fr][nf2][rr] *= alpha;
        }
#pragma unroll
        for (int rr = 0; rr < 4; ++rr) {
          const int row = fr * 16 + l4 * 4 + rr;
#pragma unroll
          for (int nf = 0; nf < 4; ++nf)
            ((unsigned short*)(Plds + row * 144))[nf * 16 + l15] = f2bf(sa[fr][nf][rr]);
        }
      }

#pragma unroll
      for (int kk2 = 0; kk2 < 2; ++kk2) {
        bf16x8 ap[2];
#pragma unroll
        for (int fr = 0; fr < 2; ++fr)
          ap[fr] = *reinterpret_cast<const bf16x8*>(Plds + (fr * 16 + l15) * 144 + kk2 * 64 + l4 * 16);
#pragma unroll
        for (int nf2 = 0; nf2 < 8; ++nf2) {
          const int rowd = nf2 * 16 + l15;
          const int slot = kk2 * 4 + l4;
          const bf16x8 bv = *reinterpret_cast<const bf16x8*>(Vb + rowd * 128 + ((slot ^ (rowd & 7)) << 4));
#pragma unroll
          for (int fr = 0; fr < 2; ++fr)
            acc[fr][nf2] = __builtin_amdgcn_mfma_f32_16x16x32_bf16(ap[fr], bv, acc[fr][nf2], 0, 0, 0);
        }
      }

      if (kt + 1 < nkt) {
        asm volatile("s_waitcnt vmcnt(0)\n\ts_barrier" ::: "memory");
      }
    }

#pragma unroll
    for (int fr = 0; fr < 2; ++fr) {
#pragma unroll
      for (int rr = 0; rr < 4; ++rr) {
#pragma unroll
        for (int dd = 1; dd < 16; dd <<= 1) lr[fr][rr] += __shfl_xor(lr[fr][rr], dd);
        const float inv = 1.f / lr[fr][rr];
        const int srow = sbase + q32 * 32 + fr * 16 + l4 * 4 + rr;
        const int mrow = row_of_token[srow];
        unsigned short* orow = Og + (size_t)mrow * (NH * HD) + h * HD;
#pragma unroll
        for (int nf2 = 0; nf2 < 8; ++nf2) orow[nf2 * 16 + l15] = f2bf(acc[fr][nf2][rr] * inv);
      }
    }

    if (pass == 0) {
      asm volatile("s_waitcnt vmcnt(0) lgkmcnt(0)\n\ts_barrier" ::: "memory");
    }
  }
}

// ---------------------------------------------------------------- launch
extern "C" void kernel_launch(void* const* d_in, const int* in_sizes, int n_in,
                              void* d_out, int out_size, void* d_ws, size_t ws_size,
                              hipStream_t stream) {
  const float* X = (const float*)d_in[0];
  const float* pcos = (const float*)d_in[1];
  const float* psin = (const float*)d_in[2];
  const int* und = (const int*)d_in[3];
  const int* geo = (const int*)d_in[4];
  const int nu = in_sizes[3], ng = in_sizes[4];
  const int S = in_sizes[0] / HIDDEN;

  const float* qw[2] = {(const float*)d_in[6], (const float*)d_in[15]};
  const float* qb[2] = {(const float*)d_in[7], (const float*)d_in[16]};
  const float* kw[2] = {(const float*)d_in[8], (const float*)d_in[17]};
  const float* kb[2] = {(const float*)d_in[9], (const float*)d_in[18]};
  const float* vw[2] = {(const float*)d_in[10], (const float*)d_in[19]};
  const float* vb[2] = {(const float*)d_in[11], (const float*)d_in[20]};
  const float* ow[2] = {(const float*)d_in[12], (const float*)d_in[21]};
  const float* qn[2] = {(const float*)d_in[13], (const float*)d_in[22]};
  const float* kn[2] = {(const float*)d_in[14], (const float*)d_in[23]};

  char* ws = (char*)d_ws;
  size_t off = 0;
  auto alloc = [&](size_t bytes) {
    char* p = ws + off;
    off = (off + bytes + 255) & ~(size_t)255;
    return p;
  };
  int* row_of_token = (int*)alloc((size_t)S * 4);
  int* tok_of_row = (int*)alloc((size_t)S * 4);
  int* mod_of_token = (int*)alloc((size_t)S * 4);
  unsigned short* Wqkv[2] = {(unsigned short*)alloc((size_t)NQKV * HIDDEN * 2),
                             (unsigned short*)alloc((size_t)NQKV * HIDDEN * 2)};
  unsigned short* Wo[2] = {(unsigned short*)alloc((size_t)HIDDEN * HIDDEN * 2),
                           (unsigned short*)alloc((size_t)HIDDEN * HIDDEN * 2)};
  unsigned short* Xg = (unsigned short*)alloc((size_t)S * HIDDEN * 2);
  unsigned short* Yqkv = (unsigned short*)alloc((size_t)S * NQKV * 2);
  unsigned short* Qr = (unsigned short*)alloc((size_t)NH * S * HD * 2);
  unsigned short* Kr = (unsigned short*)alloc((size_t)NKV * S * HD * 2);
  unsigned short* Vt = (unsigned short*)alloc((size_t)NKV * S * HD * 2);
  unsigned short* Og = (unsigned short*)alloc((size_t)S * NH * HD * 2);
  (void)ws_size; (void)n_in; (void)out_size;

  build_maps_kernel<<<(S + 255) / 256, 256, 0, stream>>>(und, geo, nu, ng,
                                                         row_of_token, tok_of_row, mod_of_token);
  {
    // full weight convert (8 segments) + X gather tail in one launch
    Cvt8 ca;
    const float* srcs[8] = {qw[0], kw[0], vw[0], ow[0], qw[1], kw[1], vw[1], ow[1]};
    unsigned short* dsts[8] = {
        Wqkv[0], Wqkv[0] + (size_t)NH * HD * HIDDEN, Wqkv[0] + (size_t)(NH + NKV) * HD * HIDDEN, Wo[0],
        Wqkv[1], Wqkv[1] + (size_t)NH * HD * HIDDEN, Wqkv[1] + (size_t)(NH + NKV) * HD * HIDDEN, Wo[1]};
    const int n4s[8] = {NH * HD * HIDDEN / 4, NKV * HD * HIDDEN / 4, NKV * HD * HIDDEN / 4, HIDDEN * HIDDEN / 4,
                        NH * HD * HIDDEN / 4, NKV * HD * HIDDEN / 4, NKV * HD * HIDDEN / 4, HIDDEN * HIDDEN / 4};
    int cum = 0;
    for (int i = 0; i < 8; ++i) { ca.src[i] = srcs[i]; ca.dst[i] = dsts[i]; ca.cum[i] = cum; cum += n4s[i]; }
    const int gather4 = S * (HIDDEN / 4);
    convert_gather_kernel<<<2048, 256, 0, stream>>>(ca, cum, X, tok_of_row, Xg, cum + gather4);
  }

  const int maxM = (nu > ng ? nu : ng);
  {
    // QKV: 12 waves (4x3), BN=288 (NF=6) -> 16x8x2 = 256 blocks, one round
    const int NX = NQKV / 288, NY = (maxM + 255) / 256;
    gemm2_kernel<0, 768, 4, 3, 6><<<dim3(NX, NY, 2), 768, 0, stream>>>(
        Xg, Wqkv[0], Wqkv[1], qb[0], kb[0], vb[0], qb[1], kb[1], vb[1],
        Yqkv, nullptr, nullptr, nu, ng, NQKV, HIDDEN, NX, NY);
  }

  norm_rope_kernel<<<S, 64, 0, stream>>>(Yqkv, row_of_token, mod_of_token, pcos, psin,
                                         qn[0], kn[0], qn[1], kn[1], Qr, Kr, Vt, S);

  attn7_kernel<<<dim3(16, NKV, S / LSAMP), 448, 0, stream>>>(Qr, Kr, Vt, row_of_token, Og, S);

  {
    // O-proj: 8 waves (4x2), BN=224 (NF=7) -> 16x8x2 = 256 blocks, one round
    const int NX = HIDDEN / 224, NY = (maxM + 255) / 256;
    gemm2_kernel<1, 512, 4, 2, 7><<<dim3(NX, NY, 2), 512, 0, stream>>>(
        Og, Wo[0], Wo[1], nullptr, nullptr, nullptr, nullptr, nullptr, nullptr,
        nullptr, (float*)d_out, tok_of_row, nu, ng, HIDDEN, HIDDEN, NX, NY);
  }
}